// Round 13
// baseline (503.244 us; speedup 1.0000x reference)
//
#include <hip/hip_runtime.h>
#include <hip/hip_fp16.h>
#include <math.h>

#define NEGSLOPE 0.2f

typedef _Float16 f16x8 __attribute__((ext_vector_type(8)));
typedef _Float16 f16x2 __attribute__((ext_vector_type(2)));
typedef float f32x4 __attribute__((ext_vector_type(4)));

__device__ __forceinline__ float lrelu(float x) { return x > 0.f ? x : NEGSLOPE * x; }

__device__ __forceinline__ float dot2acc(f16x2 a, f16x2 b, float c) {
#if __has_builtin(__builtin_amdgcn_fdot2)
    return __builtin_amdgcn_fdot2(a, b, c, false);
#else
    return c + (float)a[0] * (float)b[0] + (float)a[1] * (float)b[1];
#endif
}

// ---------------- prep: zero deg/pacc/hist + x->fp16 + weight transpose ------
__global__ __launch_bounds__(256) void k_prep(
        const float* __restrict__ x, _Float16* __restrict__ xh, int n8, int XB,
        const float* W0, const float* W1, const float* W2,
        const float* W3, const float* W4, const float* W5,
        _Float16* D0, _Float16* D1, _Float16* D2,
        _Float16* D3, _Float16* D4, _Float16* D5,
        int* __restrict__ zbase, int nzero) {
    int b = blockIdx.x, t = threadIdx.x;
    if (b < XB) {
        int i = b * 256 + t;
        if (i < n8) {
            float4 a = ((const float4*)x)[2 * i], c = ((const float4*)x)[2 * i + 1];
            union { uint4 u; _Float16 h[8]; } pk;
            pk.h[0] = (_Float16)a.x; pk.h[1] = (_Float16)a.y;
            pk.h[2] = (_Float16)a.z; pk.h[3] = (_Float16)a.w;
            pk.h[4] = (_Float16)c.x; pk.h[5] = (_Float16)c.y;
            pk.h[6] = (_Float16)c.z; pk.h[7] = (_Float16)c.w;
            ((uint4*)xh)[i] = pk.u;
        }
    } else if (b < XB + 320) {
        const float* Ws[6] = {W0, W1, W2, W3, W4, W5};
        _Float16* Ds[6] = {D0, D1, D2, D3, D4, D5};
        int j = (b - XB) * 256 + t;
        int m, jj, kout;
        if (j < 65536) { m = j >> 14; jj = j & 16383; kout = 128; }
        else           { m = 4 + ((j - 65536) >> 13); jj = (j - 65536) & 8191; kout = 64; }
        int col = jj >> 7, k = jj & 127;
        Ds[m][col * 128 + k] = (_Float16)Ws[m][k * kout + col];
    } else {
        int i = (b - XB - 320) * 256 + t;
        if (i < nzero) zbase[i] = 0;   // deg + pacc + ghist (contiguous)
    }
}

// ---------------- CSR build ----------------
// count: atomic return value = edge's rank within its target row
__global__ void k_count(const int* __restrict__ tgt, int* __restrict__ deg,
                        int* __restrict__ rank, int e) {
    int i = blockIdx.x * 256 + threadIdx.x;
    if (i < e) rank[i] = atomicAdd(&deg[tgt[i]], 1);
}
// block scans 4096 elements (256 threads x 16); +1 folds in the self-loop.
// Also accumulates the 64-bucket degree histogram (for load-balanced perm).
__global__ __launch_bounds__(256) void k_scanA(const int* __restrict__ deg, int* __restrict__ rowptr,
                                               int* __restrict__ bsums, int* __restrict__ ghist, int n) {
    __shared__ int s[256];
    __shared__ int lh[64];
    int t = threadIdx.x;
    if (t < 64) lh[t] = 0;
    int base = blockIdx.x * 4096 + t * 16;
    int pre[16];
    int sum = 0;
    __syncthreads();
    for (int i = 0; i < 16; ++i) {
        int idx = base + i;
        int v = 0;
        if (idx < n) {
            v = deg[idx] + 1;
            atomicAdd(&lh[v < 63 ? v : 63], 1);
        }
        pre[i] = sum;
        sum += v;
    }
    s[t] = sum;
    __syncthreads();
    for (int off = 1; off < 256; off <<= 1) {
        int v = (t >= off) ? s[t - off] : 0;
        __syncthreads();
        s[t] += v;
        __syncthreads();
    }
    int tbase = s[t] - sum;
    for (int i = 0; i < 16; ++i) {
        int idx = base + i;
        if (idx < n) rowptr[idx] = tbase + pre[i];
    }
    if (t == 0) bsums[blockIdx.x] = s[255];
    if (t < 64 && lh[t]) atomicAdd(&ghist[t], lh[t]);
}
// bucket cursor init: exclusive prefix of ghist
__global__ void k_binit(const int* __restrict__ ghist, int* __restrict__ cursor) {
    if (threadIdx.x == 0) {
        int run = 0;
        for (int b = 0; b < 64; ++b) { cursor[b] = run; run += ghist[b]; }
    }
}
// fused scanB+scanC: finalize rowptr, seed self-loop, build degree-sorted perm
__global__ __launch_bounds__(256) void k_scanC(int* __restrict__ rowptr, const int* __restrict__ bsums,
                                               int* __restrict__ edst, const int* __restrict__ deg,
                                               int* __restrict__ cursor, int* __restrict__ perm,
                                               int nscan, int n) {
    __shared__ int pref[65];
    int t = threadIdx.x;
    if (t == 0) {
        int run = 0;
        for (int k = 0; k < nscan; ++k) { pref[k] = run; run += bsums[k]; }
        pref[nscan] = run;
    }
    __syncthreads();
    int i = blockIdx.x * 256 + t;
    if (i < n) {
        int rp = rowptr[i] + pref[i >> 12];
        rowptr[i] = rp;
        edst[rp] = i;                          // self loop first in each row
        int d = deg[i] + 1;
        int p = atomicAdd(&cursor[d < 63 ? d : 63], 1);
        perm[p] = i;
    }
    if (blockIdx.x == gridDim.x - 1 && t == 0) rowptr[n] = pref[nscan];
}
// scatter: no atomics; slot = rowptr[tgt] + 1 + rank
__global__ void k_scatter(const int* __restrict__ src, const int* __restrict__ tgt,
                          const int* __restrict__ rank, const int* __restrict__ rowptr,
                          int* __restrict__ edst, int e) {
    int i = blockIdx.x * 256 + threadIdx.x;
    if (i < e) {
        int p = rowptr[tgt[i]] + 1 + rank[i];
        __builtin_nontemporal_store(src[i], &edst[p]);
    }
}

// ---------------- MFMA fp16 GEMM: out0 = f16(A@W0), out1 = f16(A@W1) ---------
template<int KOUT>
__global__ __launch_bounds__(256) void k_gemm_mfma(
        const _Float16* __restrict__ Ah,
        const _Float16* __restrict__ Wt0, const _Float16* __restrict__ Wt1,
        _Float16* __restrict__ out0, _Float16* __restrict__ out1, int n) {
    int wv = threadIdx.x >> 6, lane = threadIdx.x & 63;
    int m = lane & 15, q = lane >> 4;
    int row0 = blockIdx.x * 64 + wv * 16;
    int arow = row0 + m; if (arow >= n) arow = n - 1;
    const _Float16* ap = Ah + (size_t)arow * 128 + q * 8;
    f16x8 af[4];
#pragma unroll
    for (int kt = 0; kt < 4; ++kt) af[kt] = *(const f16x8*)(ap + 32 * kt);

    const _Float16* Wp = Wt0;
    _Float16* outp = out0;
    if (KOUT == 128 && blockIdx.y) { Wp = Wt1; outp = out1; }

    f32x4 acc[8] = {};
#pragma unroll
    for (int kt = 0; kt < 4; ++kt) {
        f16x8 bfr[8];
#pragma unroll
        for (int ct = 0; ct < 8; ++ct) {
            const _Float16* W = (KOUT == 128) ? Wp : (ct < 4 ? Wt0 : Wt1);
            int col0 = (KOUT == 128) ? ct * 16 : (ct & 3) * 16;
            bfr[ct] = *(const f16x8*)(W + (size_t)(col0 + m) * 128 + 32 * kt + 8 * q);
        }
#pragma unroll
        for (int ct = 0; ct < 8; ++ct)
            acc[ct] = __builtin_amdgcn_mfma_f32_16x16x32_f16(af[kt], bfr[ct], acc[ct], 0, 0, 0);
    }
#pragma unroll
    for (int ct = 0; ct < 8; ++ct) {
        _Float16* dst = (KOUT == 128) ? outp : (ct < 4 ? out0 : out1);
        int col = ((KOUT == 128) ? ct * 16 : (ct & 3) * 16) + m;
#pragma unroll
        for (int i = 0; i < 4; ++i) {
            int r = row0 + q * 4 + i;
            if (r < n) dst[(size_t)r * KOUT + col] = (_Float16)acc[ct][i];
        }
    }
}

// ---------------- GATv2 aggregation: 4 nodes/wave, 16 lanes/node --------------
// Degree-sorted perm -> the 4 nodes in a wave have near-equal degree (no waste).
// Score path in packed f16 ext-vector ops (v_pk_add/mul/max + fdot2); accum f32.
template<int H, int C, typename OutT>
__global__ __launch_bounds__(256) void k_agg(const _Float16* __restrict__ xl, const _Float16* __restrict__ xr,
                                             const float* __restrict__ att, const float* __restrict__ bias,
                                             const int* __restrict__ rowptr, const int* __restrict__ edst,
                                             const int* __restrict__ perm,
                                             OutT* __restrict__ yout, int n) {
    constexpr int F = H * C;
    constexpr int VEC = F / 16;      // 8 (F=128) or 4 (F=64)
    constexpr int NH2 = VEC / 2;     // f16x2 per lane: 4 or 2
    constexpr int L = C / VEC;       // lanes per head: 4 or 16
    int lane = threadIdx.x & 63;
    int wave = threadIdx.x >> 6;
    int s = lane & 15;
    int gid = blockIdx.x * 16 + wave * 4 + (lane >> 4);
    bool valid = gid < n;
    int node = valid ? perm[gid] : 0;
    int ch = s * VEC;

    f16x2 u2[NH2], av2[NH2];
    {
        union { uint4 u4; uint2 u2v; f16x2 h[4]; } pk;
        if constexpr (NH2 == 4) pk.u4 = *(const uint4*)(xr + (size_t)node * F + ch);
        else pk.u2v = *(const uint2*)(xr + (size_t)node * F + ch);
#pragma unroll
        for (int j = 0; j < NH2; ++j) u2[j] = pk.h[j];
    }
#pragma unroll
    for (int j = 0; j < NH2; ++j) {
        av2[j][0] = (_Float16)att[ch + 2 * j];
        av2[j][1] = (_Float16)att[ch + 2 * j + 1];
    }

    float acc[VEC];
#pragma unroll
    for (int j = 0; j < VEC; ++j) acc[j] = 0.f;
    int e0 = rowptr[node];
    int deg = valid ? (rowptr[node + 1] - e0) : 0;
    int maxdeg = deg;
    maxdeg = max(maxdeg, __shfl_xor(maxdeg, 16));
    maxdeg = max(maxdeg, __shfl_xor(maxdeg, 32));
    float ssum = 0.f;

    const _Float16 cneg = (_Float16)NEGSLOPE;
    auto edge = [&](int srcRow, bool live) {
        union { uint4 u4; uint2 u2v; f16x2 hh[4]; } pk;
        const _Float16* p = xl + (size_t)srcRow * F + ch;
        if constexpr (NH2 == 4) pk.u4 = *(const uint4*)p;
        else pk.u2v = *(const uint2*)p;
        float sc = 0.f;
#pragma unroll
        for (int j = 0; j < NH2; ++j) {
            f16x2 t = pk.hh[j] + u2[j];                       // v_pk_add_f16
            f16x2 lr = __builtin_elementwise_max(t, t * cneg); // pk_mul + pk_max
            sc = dot2acc(lr, av2[j], sc);
        }
#pragma unroll
        for (int off = 1; off < L; off <<= 1) sc += __shfl_xor(sc, off);
        float w = live ? __expf(sc) : 0.f;
        ssum += w;
#pragma unroll
        for (int j = 0; j < NH2; ++j) {
            acc[2 * j]     += w * (float)pk.hh[j][0];
            acc[2 * j + 1] += w * (float)pk.hh[j][1];
        }
    };

    for (int base = 0; base < maxdeg; base += 16) {
        int cnt = deg - base;
        if (cnt > 16) cnt = 16;
        int idxreg = (s < cnt) ? edst[e0 + base + s] : node;
        int mcnt = cnt;
        mcnt = max(mcnt, __shfl_xor(mcnt, 16));
        mcnt = max(mcnt, __shfl_xor(mcnt, 32));
        int gbase = lane & 48;
        int i = 0;
        for (; i + 2 <= mcnt; i += 2) {
            int s0 = __shfl(idxreg, gbase + i);
            int s1 = __shfl(idxreg, gbase + i + 1);
            edge(s0, i < cnt);
            edge(s1, i + 1 < cnt);
        }
        for (; i < mcnt; ++i) {
            int s0 = __shfl(idxreg, gbase + i);
            edge(s0, i < cnt);
        }
    }
    if (valid) {
        float inv = 1.f / ssum;
        float o[VEC];
#pragma unroll
        for (int j = 0; j < VEC; ++j) o[j] = lrelu(acc[j] * inv + bias[ch + j]);
        if constexpr (sizeof(OutT) == 2) {
            _Float16* p = (_Float16*)yout + (size_t)node * F + ch;
            if constexpr (VEC == 8) {
                union { uint4 u; _Float16 h[8]; } pk;
#pragma unroll
                for (int j = 0; j < 8; ++j) pk.h[j] = (_Float16)o[j];
                *(uint4*)p = pk.u;
            } else {
                union { uint2 u; _Float16 h[4]; } pk;
#pragma unroll
                for (int j = 0; j < 4; ++j) pk.h[j] = (_Float16)o[j];
                *(uint2*)p = pk.u;
            }
        } else {
            float* p = (float*)yout + (size_t)node * F + ch;
            *(float4*)p = make_float4(o[0], o[1], o[2], o[3]);
            if constexpr (VEC == 8)
                *(float4*)(p + 4) = make_float4(o[4], o[5], o[6], o[7]);
        }
    }
}

// ---------------- hierarchical global mean pool ----------------
__global__ __launch_bounds__(256) void k_pool_partial(const float* __restrict__ y,
        const int* __restrict__ batch, float* __restrict__ pacc, int n, int nchunk) {
    __shared__ float sdata[256];
    __shared__ int range[2];
    int g = blockIdx.x;
    int chunk = blockIdx.y;
    int t = threadIdx.x;
    if (t == 0) {
        int lo = 0, hi = n;
        while (lo < hi) { int mid = (lo + hi) >> 1; if (batch[mid] < g) lo = mid + 1; else hi = mid; }
        range[0] = lo;
        hi = n;
        while (lo < hi) { int mid = (lo + hi) >> 1; if (batch[mid] < g + 1) lo = mid + 1; else hi = mid; }
        range[1] = lo;
    }
    __syncthreads();
    int start = range[0], len = range[1] - range[0];
    int lo = start + (int)((long long)len * chunk / nchunk);
    int hi = start + (int)((long long)len * (chunk + 1) / nchunk);
    int ch = t & 63, sub = t >> 6;
    float acc = 0.f;
    for (int node = lo + sub; node < hi; node += 4)
        acc += y[(size_t)node * 64 + ch];
    sdata[t] = acc;
    __syncthreads();
    if (t < 128) sdata[t] += sdata[t + 128];
    __syncthreads();
    if (t < 64) atomicAdd(&pacc[g * 64 + t], sdata[t] + sdata[t + 64]);
}
__global__ void k_pool_final(const float* __restrict__ pacc, const int* __restrict__ batch,
                             float* __restrict__ out, int n) {
    __shared__ int cntS;
    int g = blockIdx.x, t = threadIdx.x;
    if (t == 0) {
        int lo = 0, hi = n;
        while (lo < hi) { int mid = (lo + hi) >> 1; if (batch[mid] < g) lo = mid + 1; else hi = mid; }
        int s = lo;
        hi = n;
        while (lo < hi) { int mid = (lo + hi) >> 1; if (batch[mid] < g + 1) lo = mid + 1; else hi = mid; }
        cntS = lo - s;
    }
    __syncthreads();
    out[g * 64 + t] = pacc[g * 64 + t] / fmaxf((float)cntS, 1.f);
}

extern "C" void kernel_launch(void* const* d_in, const int* in_sizes, int n_in,
                              void* d_out, int out_size, void* d_ws, size_t ws_size,
                              hipStream_t stream) {
    const float* x     = (const float*)d_in[0];
    const int*   ei    = (const int*)d_in[1];
    const int*   batch = (const int*)d_in[2];
    const float* Wl0 = (const float*)d_in[3];
    const float* Wr0 = (const float*)d_in[4];
    const float* att0 = (const float*)d_in[5];
    const float* b0  = (const float*)d_in[6];
    const float* Wl1 = (const float*)d_in[7];
    const float* Wr1 = (const float*)d_in[8];
    const float* att1 = (const float*)d_in[9];
    const float* b1  = (const float*)d_in[10];
    const float* Wl2 = (const float*)d_in[11];
    const float* Wr2 = (const float*)d_in[12];
    const float* att2 = (const float*)d_in[13];
    const float* b2  = (const float*)d_in[14];

    const int N = in_sizes[2];        // 50000
    const int E = in_sizes[1] / 2;    // 800000
    const int G = out_size / 64;      // 64
    const int* src = ei;
    const int* tgt = ei + E;

    size_t off = 0;
    auto take = [&](size_t bytes) {
        void* p = (char*)d_ws + off;
        off = (off + bytes + 255) & ~(size_t)255;
        return p;
    };
    _Float16* xh   = (_Float16*)take((size_t)N * 128 * 2);
    _Float16* Ah   = (_Float16*)take((size_t)N * 128 * 2); // xl
    _Float16* B    = (_Float16*)take((size_t)N * 128 * 2); // xr
    _Float16* Cbh  = (_Float16*)take((size_t)N * 128 * 2); // agg out layers 0/1
    float* Cbf     = (float*)take((size_t)N * 64 * 4);     // agg out layer 2
    _Float16* Wl0t = (_Float16*)take(128 * 128 * 2);
    _Float16* Wr0t = (_Float16*)take(128 * 128 * 2);
    _Float16* Wl1t = (_Float16*)take(128 * 128 * 2);
    _Float16* Wr1t = (_Float16*)take(128 * 128 * 2);
    _Float16* Wl2t = (_Float16*)take(64 * 128 * 2);
    _Float16* Wr2t = (_Float16*)take(64 * 128 * 2);
    int* rowptr = (int*)take((size_t)(N + 1) * 4);
    // contiguous zero region: deg(N) + pacc(G*64) + ghist(64)
    int* tmp    = (int*)take((size_t)N * 4);
    float* pacc = (float*)take((size_t)G * 64 * 4);
    int* ghist  = (int*)take(64 * 4);
    int* cursor = (int*)take(64 * 4);
    int* perm   = (int*)take((size_t)N * 4);
    int* rank   = (int*)take((size_t)E * 4);
    int* edst   = (int*)take((size_t)(E + N) * 4);
    int* bsums  = (int*)take(64 * 4);
    (void)ws_size; (void)n_in;

    const int TB = 256;
    int nblkN = (N + TB - 1) / TB;
    int nblkE = (E + TB - 1) / TB;
    int nscan = (N + 4095) / 4096;

    // --- prep: zeroing + fp16 conversions (one launch) ---
    int n8 = N * 128 / 8;
    int XB = (n8 + TB - 1) / TB;
    int nzero = (int)(((char*)(cursor)) - (char*)tmp) / 4;   // deg+pacc+ghist (+pad)
    int ZB = (nzero + TB - 1) / TB;
    k_prep<<<XB + 320 + ZB, TB, 0, stream>>>(x, xh, n8, XB,
        Wl0, Wr0, Wl1, Wr1, Wl2, Wr2,
        Wl0t, Wr0t, Wl1t, Wr1t, Wl2t, Wr2t,
        tmp, nzero);

    // --- CSR build + degree-sorted perm ---
    k_count<<<nblkE, TB, 0, stream>>>(tgt, tmp, rank, E);
    k_scanA<<<nscan, TB, 0, stream>>>(tmp, rowptr, bsums, ghist, N);
    k_binit<<<1, 64, 0, stream>>>(ghist, cursor);
    k_scanC<<<nblkN, TB, 0, stream>>>(rowptr, bsums, edst, tmp, cursor, perm, nscan, N);
    k_scatter<<<nblkE, TB, 0, stream>>>(src, tgt, rank, rowptr, edst, E);

    int gemmBlocks = (N + 63) / 64;
    dim3 gemmGrid2(gemmBlocks, 2);
    dim3 gemmGrid1(gemmBlocks, 1);
    int aggBlocks = (N + 15) / 16;

    // --- layer 0 ---
    k_gemm_mfma<128><<<gemmGrid2, TB, 0, stream>>>(xh, Wl0t, Wr0t, Ah, B, N);
    k_agg<4, 32, _Float16><<<aggBlocks, TB, 0, stream>>>(Ah, B, att0, b0, rowptr, edst, perm, Cbh, N);

    // --- layer 1 ---
    k_gemm_mfma<128><<<gemmGrid2, TB, 0, stream>>>(Cbh, Wl1t, Wr1t, Ah, B, N);
    k_agg<4, 32, _Float16><<<aggBlocks, TB, 0, stream>>>(Ah, B, att1, b1, rowptr, edst, perm, Cbh, N);

    // --- layer 2 ---
    k_gemm_mfma<64><<<gemmGrid1, TB, 0, stream>>>(Cbh, Wl2t, Wr2t, Ah, B, N);
    k_agg<1, 64, float><<<aggBlocks, TB, 0, stream>>>(Ah, B, att2, b2, rowptr, edst, perm, Cbf, N);

    // --- hierarchical global mean pool ---
    dim3 poolGrid(G, 16);
    k_pool_partial<<<poolGrid, TB, 0, stream>>>(Cbf, batch, pacc, N, 16);
    k_pool_final<<<G, 64, 0, stream>>>(pacc, batch, (float*)d_out, N);
}

// Round 14
// 380.032 us; speedup vs baseline: 1.3242x; 1.3242x over previous
//
#include <hip/hip_runtime.h>
#include <hip/hip_fp16.h>
#include <math.h>

#define NEGSLOPE 0.2f

typedef _Float16 f16x8 __attribute__((ext_vector_type(8)));
typedef _Float16 f16x2 __attribute__((ext_vector_type(2)));
typedef float f32x4 __attribute__((ext_vector_type(4)));

__device__ __forceinline__ float lrelu(float x) { return x > 0.f ? x : NEGSLOPE * x; }

__device__ __forceinline__ float dot2acc(f16x2 a, f16x2 b, float c) {
#if __has_builtin(__builtin_amdgcn_fdot2)
    return __builtin_amdgcn_fdot2(a, b, c, false);
#else
    return c + (float)a[0] * (float)b[0] + (float)a[1] * (float)b[1];
#endif
}

// ---------------- prep: zero deg/pacc + x->fp16 + weight transpose -----------
__global__ __launch_bounds__(256) void k_prep(
        const float* __restrict__ x, _Float16* __restrict__ xh, int n8, int XB,
        const float* W0, const float* W1, const float* W2,
        const float* W3, const float* W4, const float* W5,
        _Float16* D0, _Float16* D1, _Float16* D2,
        _Float16* D3, _Float16* D4, _Float16* D5,
        int* __restrict__ zbase, int nzero) {
    int b = blockIdx.x, t = threadIdx.x;
    if (b < XB) {
        int i = b * 256 + t;
        if (i < n8) {
            float4 a = ((const float4*)x)[2 * i], c = ((const float4*)x)[2 * i + 1];
            union { uint4 u; _Float16 h[8]; } pk;
            pk.h[0] = (_Float16)a.x; pk.h[1] = (_Float16)a.y;
            pk.h[2] = (_Float16)a.z; pk.h[3] = (_Float16)a.w;
            pk.h[4] = (_Float16)c.x; pk.h[5] = (_Float16)c.y;
            pk.h[6] = (_Float16)c.z; pk.h[7] = (_Float16)c.w;
            ((uint4*)xh)[i] = pk.u;
        }
    } else if (b < XB + 320) {
        const float* Ws[6] = {W0, W1, W2, W3, W4, W5};
        _Float16* Ds[6] = {D0, D1, D2, D3, D4, D5};
        int j = (b - XB) * 256 + t;
        int m, jj, kout;
        if (j < 65536) { m = j >> 14; jj = j & 16383; kout = 128; }
        else           { m = 4 + ((j - 65536) >> 13); jj = (j - 65536) & 8191; kout = 64; }
        int col = jj >> 7, k = jj & 127;
        Ds[m][col * 128 + k] = (_Float16)Ws[m][k * kout + col];
    } else {
        int i = (b - XB - 320) * 256 + t;
        if (i < nzero) zbase[i] = 0;   // deg + pacc (contiguous)
    }
}

// ---------------- CSR build ----------------
// count: atomic return value = edge's rank within its target row
__global__ void k_count(const int* __restrict__ tgt, int* __restrict__ deg,
                        int* __restrict__ rank, int e) {
    int i = blockIdx.x * 256 + threadIdx.x;
    if (i < e) rank[i] = atomicAdd(&deg[tgt[i]], 1);
}
// block scans 4096 elements (256 threads x 16); +1 folds in the self-loop.
// Stores the per-block 64-bucket degree histogram (owned row, no atomics).
__global__ __launch_bounds__(256) void k_scanA(const int* __restrict__ deg, int* __restrict__ rowptr,
                                               int* __restrict__ bsums, int* __restrict__ bhist, int n) {
    __shared__ int s[256];
    __shared__ int lh[64];
    int t = threadIdx.x;
    if (t < 64) lh[t] = 0;
    int base = blockIdx.x * 4096 + t * 16;
    int pre[16];
    int sum = 0;
    __syncthreads();
    for (int i = 0; i < 16; ++i) {
        int idx = base + i;
        int v = 0;
        if (idx < n) {
            v = deg[idx] + 1;
            atomicAdd(&lh[v < 63 ? v : 63], 1);   // LDS atomic — cheap
        }
        pre[i] = sum;
        sum += v;
    }
    s[t] = sum;
    __syncthreads();
    for (int off = 1; off < 256; off <<= 1) {
        int v = (t >= off) ? s[t - off] : 0;
        __syncthreads();
        s[t] += v;
        __syncthreads();
    }
    int tbase = s[t] - sum;
    for (int i = 0; i < 16; ++i) {
        int idx = base + i;
        if (idx < n) rowptr[idx] = tbase + pre[i];
    }
    if (t == 0) bsums[blockIdx.x] = s[255];
    if (t < 64) bhist[blockIdx.x * 64 + t] = lh[t];
}
// bucket offsets: boff[sb][b] = global bucket base + prefix over scan-blocks.
// One block, 64 threads; nscan<=16 -> trivial.
__global__ void k_binit(const int* __restrict__ bhist, int* __restrict__ boff, int nscan) {
    __shared__ int tots[64];
    __shared__ int base[64];
    int b = threadIdx.x;
    int tot = 0;
    for (int sb = 0; sb < nscan; ++sb) {
        boff[sb * 64 + b] = tot;
        tot += bhist[sb * 64 + b];
    }
    tots[b] = tot;
    __syncthreads();
    if (b == 0) {
        int run = 0;
        for (int k = 0; k < 64; ++k) { base[k] = run; run += tots[k]; }
    }
    __syncthreads();
    for (int sb = 0; sb < nscan; ++sb) boff[sb * 64 + b] += base[b];
}
// fused scanB+scanC: same 4096-node blocking as scanA. Finalize rowptr, seed
// self-loop, build degree-sorted perm via LDS cursor (no global atomic contention).
__global__ __launch_bounds__(256) void k_scanC(int* __restrict__ rowptr, const int* __restrict__ bsums,
                                               int* __restrict__ edst, const int* __restrict__ deg,
                                               const int* __restrict__ boff, int* __restrict__ perm,
                                               int nscan, int n) {
    __shared__ int pref[17];
    __shared__ int cur[64];
    int t = threadIdx.x;
    if (t == 0) {
        int run = 0;
        for (int k = 0; k < nscan; ++k) { pref[k] = run; run += bsums[k]; }
        pref[nscan] = run;
    }
    if (t < 64) cur[t] = boff[blockIdx.x * 64 + t];
    __syncthreads();
    int myoff = pref[blockIdx.x];
    int base = blockIdx.x * 4096 + t * 16;
    for (int i = 0; i < 16; ++i) {
        int idx = base + i;
        if (idx < n) {
            int rp = rowptr[idx] + myoff;
            rowptr[idx] = rp;
            edst[rp] = idx;                    // self loop first in each row
            int d = deg[idx] + 1;
            int slot = atomicAdd(&cur[d < 63 ? d : 63], 1);   // LDS atomic
            perm[slot] = idx;
        }
    }
    if (blockIdx.x == gridDim.x - 1 && t == 0) rowptr[n] = pref[nscan];
}
// scatter: no atomics; slot = rowptr[tgt] + 1 + rank
__global__ void k_scatter(const int* __restrict__ src, const int* __restrict__ tgt,
                          const int* __restrict__ rank, const int* __restrict__ rowptr,
                          int* __restrict__ edst, int e) {
    int i = blockIdx.x * 256 + threadIdx.x;
    if (i < e) {
        int p = rowptr[tgt[i]] + 1 + rank[i];
        __builtin_nontemporal_store(src[i], &edst[p]);
    }
}

// ---------------- MFMA fp16 GEMM: out0 = f16(A@W0), out1 = f16(A@W1) ---------
template<int KOUT>
__global__ __launch_bounds__(256) void k_gemm_mfma(
        const _Float16* __restrict__ Ah,
        const _Float16* __restrict__ Wt0, const _Float16* __restrict__ Wt1,
        _Float16* __restrict__ out0, _Float16* __restrict__ out1, int n) {
    int wv = threadIdx.x >> 6, lane = threadIdx.x & 63;
    int m = lane & 15, q = lane >> 4;
    int row0 = blockIdx.x * 64 + wv * 16;
    int arow = row0 + m; if (arow >= n) arow = n - 1;
    const _Float16* ap = Ah + (size_t)arow * 128 + q * 8;
    f16x8 af[4];
#pragma unroll
    for (int kt = 0; kt < 4; ++kt) af[kt] = *(const f16x8*)(ap + 32 * kt);

    const _Float16* Wp = Wt0;
    _Float16* outp = out0;
    if (KOUT == 128 && blockIdx.y) { Wp = Wt1; outp = out1; }

    f32x4 acc[8] = {};
#pragma unroll
    for (int kt = 0; kt < 4; ++kt) {
        f16x8 bfr[8];
#pragma unroll
        for (int ct = 0; ct < 8; ++ct) {
            const _Float16* W = (KOUT == 128) ? Wp : (ct < 4 ? Wt0 : Wt1);
            int col0 = (KOUT == 128) ? ct * 16 : (ct & 3) * 16;
            bfr[ct] = *(const f16x8*)(W + (size_t)(col0 + m) * 128 + 32 * kt + 8 * q);
        }
#pragma unroll
        for (int ct = 0; ct < 8; ++ct)
            acc[ct] = __builtin_amdgcn_mfma_f32_16x16x32_f16(af[kt], bfr[ct], acc[ct], 0, 0, 0);
    }
#pragma unroll
    for (int ct = 0; ct < 8; ++ct) {
        _Float16* dst = (KOUT == 128) ? outp : (ct < 4 ? out0 : out1);
        int col = ((KOUT == 128) ? ct * 16 : (ct & 3) * 16) + m;
#pragma unroll
        for (int i = 0; i < 4; ++i) {
            int r = row0 + q * 4 + i;
            if (r < n) dst[(size_t)r * KOUT + col] = (_Float16)acc[ct][i];
        }
    }
}

// ---------------- GATv2 aggregation: 4 nodes/wave, 16 lanes/node --------------
// Degree-sorted perm -> the 4 nodes in a wave have near-equal degree (no waste).
// Score path in packed f16 ext-vector ops (v_pk_add/mul/max + fdot2); accum f32.
template<int H, int C, typename OutT>
__global__ __launch_bounds__(256) void k_agg(const _Float16* __restrict__ xl, const _Float16* __restrict__ xr,
                                             const float* __restrict__ att, const float* __restrict__ bias,
                                             const int* __restrict__ rowptr, const int* __restrict__ edst,
                                             const int* __restrict__ perm,
                                             OutT* __restrict__ yout, int n) {
    constexpr int F = H * C;
    constexpr int VEC = F / 16;      // 8 (F=128) or 4 (F=64)
    constexpr int NH2 = VEC / 2;     // f16x2 per lane: 4 or 2
    constexpr int L = C / VEC;       // lanes per head: 4 or 16
    int lane = threadIdx.x & 63;
    int wave = threadIdx.x >> 6;
    int s = lane & 15;
    int gid = blockIdx.x * 16 + wave * 4 + (lane >> 4);
    bool valid = gid < n;
    int node = valid ? perm[gid] : 0;
    int ch = s * VEC;

    f16x2 u2[NH2], av2[NH2];
    {
        union { uint4 u4; uint2 u2v; f16x2 h[4]; } pk;
        if constexpr (NH2 == 4) pk.u4 = *(const uint4*)(xr + (size_t)node * F + ch);
        else pk.u2v = *(const uint2*)(xr + (size_t)node * F + ch);
#pragma unroll
        for (int j = 0; j < NH2; ++j) u2[j] = pk.h[j];
    }
#pragma unroll
    for (int j = 0; j < NH2; ++j) {
        av2[j][0] = (_Float16)att[ch + 2 * j];
        av2[j][1] = (_Float16)att[ch + 2 * j + 1];
    }

    float acc[VEC];
#pragma unroll
    for (int j = 0; j < VEC; ++j) acc[j] = 0.f;
    int e0 = rowptr[node];
    int deg = valid ? (rowptr[node + 1] - e0) : 0;
    int maxdeg = deg;
    maxdeg = max(maxdeg, __shfl_xor(maxdeg, 16));
    maxdeg = max(maxdeg, __shfl_xor(maxdeg, 32));
    float ssum = 0.f;

    const _Float16 cneg = (_Float16)NEGSLOPE;
    auto edge = [&](int srcRow, bool live) {
        union { uint4 u4; uint2 u2v; f16x2 hh[4]; } pk;
        const _Float16* p = xl + (size_t)srcRow * F + ch;
        if constexpr (NH2 == 4) pk.u4 = *(const uint4*)p;
        else pk.u2v = *(const uint2*)p;
        float sc = 0.f;
#pragma unroll
        for (int j = 0; j < NH2; ++j) {
            f16x2 t = pk.hh[j] + u2[j];                        // v_pk_add_f16
            f16x2 lr = __builtin_elementwise_max(t, t * cneg); // pk_mul + pk_max
            sc = dot2acc(lr, av2[j], sc);
        }
#pragma unroll
        for (int off = 1; off < L; off <<= 1) sc += __shfl_xor(sc, off);
        float w = live ? __expf(sc) : 0.f;
        ssum += w;
#pragma unroll
        for (int j = 0; j < NH2; ++j) {
            acc[2 * j]     += w * (float)pk.hh[j][0];
            acc[2 * j + 1] += w * (float)pk.hh[j][1];
        }
    };

    for (int base = 0; base < maxdeg; base += 16) {
        int cnt = deg - base;
        if (cnt > 16) cnt = 16;
        int idxreg = (s < cnt) ? edst[e0 + base + s] : node;
        int mcnt = cnt;
        mcnt = max(mcnt, __shfl_xor(mcnt, 16));
        mcnt = max(mcnt, __shfl_xor(mcnt, 32));
        int gbase = lane & 48;
        int i = 0;
        for (; i + 2 <= mcnt; i += 2) {
            int s0 = __shfl(idxreg, gbase + i);
            int s1 = __shfl(idxreg, gbase + i + 1);
            edge(s0, i < cnt);
            edge(s1, i + 1 < cnt);
        }
        for (; i < mcnt; ++i) {
            int s0 = __shfl(idxreg, gbase + i);
            edge(s0, i < cnt);
        }
    }
    if (valid) {
        float inv = 1.f / ssum;
        float o[VEC];
#pragma unroll
        for (int j = 0; j < VEC; ++j) o[j] = lrelu(acc[j] * inv + bias[ch + j]);
        if constexpr (sizeof(OutT) == 2) {
            _Float16* p = (_Float16*)yout + (size_t)node * F + ch;
            if constexpr (VEC == 8) {
                union { uint4 u; _Float16 h[8]; } pk;
#pragma unroll
                for (int j = 0; j < 8; ++j) pk.h[j] = (_Float16)o[j];
                *(uint4*)p = pk.u;
            } else {
                union { uint2 u; _Float16 h[4]; } pk;
#pragma unroll
                for (int j = 0; j < 4; ++j) pk.h[j] = (_Float16)o[j];
                *(uint2*)p = pk.u;
            }
        } else {
            float* p = (float*)yout + (size_t)node * F + ch;
            *(float4*)p = make_float4(o[0], o[1], o[2], o[3]);
            if constexpr (VEC == 8)
                *(float4*)(p + 4) = make_float4(o[4], o[5], o[6], o[7]);
        }
    }
}

// ---------------- hierarchical global mean pool ----------------
__global__ __launch_bounds__(256) void k_pool_partial(const float* __restrict__ y,
        const int* __restrict__ batch, float* __restrict__ pacc, int n, int nchunk) {
    __shared__ float sdata[256];
    __shared__ int range[2];
    int g = blockIdx.x;
    int chunk = blockIdx.y;
    int t = threadIdx.x;
    if (t == 0) {
        int lo = 0, hi = n;
        while (lo < hi) { int mid = (lo + hi) >> 1; if (batch[mid] < g) lo = mid + 1; else hi = mid; }
        range[0] = lo;
        hi = n;
        while (lo < hi) { int mid = (lo + hi) >> 1; if (batch[mid] < g + 1) lo = mid + 1; else hi = mid; }
        range[1] = lo;
    }
    __syncthreads();
    int start = range[0], len = range[1] - range[0];
    int lo = start + (int)((long long)len * chunk / nchunk);
    int hi = start + (int)((long long)len * (chunk + 1) / nchunk);
    int ch = t & 63, sub = t >> 6;
    float acc = 0.f;
    for (int node = lo + sub; node < hi; node += 4)
        acc += y[(size_t)node * 64 + ch];
    sdata[t] = acc;
    __syncthreads();
    if (t < 128) sdata[t] += sdata[t + 128];
    __syncthreads();
    if (t < 64) atomicAdd(&pacc[g * 64 + t], sdata[t] + sdata[t + 64]);
}
__global__ void k_pool_final(const float* __restrict__ pacc, const int* __restrict__ batch,
                             float* __restrict__ out, int n) {
    __shared__ int cntS;
    int g = blockIdx.x, t = threadIdx.x;
    if (t == 0) {
        int lo = 0, hi = n;
        while (lo < hi) { int mid = (lo + hi) >> 1; if (batch[mid] < g) lo = mid + 1; else hi = mid; }
        int s = lo;
        hi = n;
        while (lo < hi) { int mid = (lo + hi) >> 1; if (batch[mid] < g + 1) lo = mid + 1; else hi = mid; }
        cntS = lo - s;
    }
    __syncthreads();
    out[g * 64 + t] = pacc[g * 64 + t] / fmaxf((float)cntS, 1.f);
}

extern "C" void kernel_launch(void* const* d_in, const int* in_sizes, int n_in,
                              void* d_out, int out_size, void* d_ws, size_t ws_size,
                              hipStream_t stream) {
    const float* x     = (const float*)d_in[0];
    const int*   ei    = (const int*)d_in[1];
    const int*   batch = (const int*)d_in[2];
    const float* Wl0 = (const float*)d_in[3];
    const float* Wr0 = (const float*)d_in[4];
    const float* att0 = (const float*)d_in[5];
    const float* b0  = (const float*)d_in[6];
    const float* Wl1 = (const float*)d_in[7];
    const float* Wr1 = (const float*)d_in[8];
    const float* att1 = (const float*)d_in[9];
    const float* b1  = (const float*)d_in[10];
    const float* Wl2 = (const float*)d_in[11];
    const float* Wr2 = (const float*)d_in[12];
    const float* att2 = (const float*)d_in[13];
    const float* b2  = (const float*)d_in[14];

    const int N = in_sizes[2];        // 50000
    const int E = in_sizes[1] / 2;    // 800000
    const int G = out_size / 64;      // 64
    const int* src = ei;
    const int* tgt = ei + E;

    size_t off = 0;
    auto take = [&](size_t bytes) {
        void* p = (char*)d_ws + off;
        off = (off + bytes + 255) & ~(size_t)255;
        return p;
    };
    _Float16* xh   = (_Float16*)take((size_t)N * 128 * 2);
    _Float16* Ah   = (_Float16*)take((size_t)N * 128 * 2); // xl
    _Float16* B    = (_Float16*)take((size_t)N * 128 * 2); // xr
    _Float16* Cbh  = (_Float16*)take((size_t)N * 128 * 2); // agg out layers 0/1
    float* Cbf     = (float*)take((size_t)N * 64 * 4);     // agg out layer 2
    _Float16* Wl0t = (_Float16*)take(128 * 128 * 2);
    _Float16* Wr0t = (_Float16*)take(128 * 128 * 2);
    _Float16* Wl1t = (_Float16*)take(128 * 128 * 2);
    _Float16* Wr1t = (_Float16*)take(128 * 128 * 2);
    _Float16* Wl2t = (_Float16*)take(64 * 128 * 2);
    _Float16* Wr2t = (_Float16*)take(64 * 128 * 2);
    int* rowptr = (int*)take((size_t)(N + 1) * 4);
    // contiguous zero region: deg(N) + pacc(G*64)
    int* tmp    = (int*)take((size_t)N * 4);
    float* pacc = (float*)take((size_t)G * 64 * 4);
    int* bhist  = (int*)take(16 * 64 * 4);
    int* boff   = (int*)take(16 * 64 * 4);
    int* perm   = (int*)take((size_t)N * 4);
    int* rank   = (int*)take((size_t)E * 4);
    int* edst   = (int*)take((size_t)(E + N) * 4);
    int* bsums  = (int*)take(64 * 4);
    (void)ws_size; (void)n_in;

    const int TB = 256;
    int nblkE = (E + TB - 1) / TB;
    int nscan = (N + 4095) / 4096;

    // --- prep: zeroing + fp16 conversions (one launch) ---
    int n8 = N * 128 / 8;
    int XB = (n8 + TB - 1) / TB;
    int nzero = (int)(((char*)bhist) - (char*)tmp) / 4;   // deg+pacc (+pad)
    int ZB = (nzero + TB - 1) / TB;
    k_prep<<<XB + 320 + ZB, TB, 0, stream>>>(x, xh, n8, XB,
        Wl0, Wr0, Wl1, Wr1, Wl2, Wr2,
        Wl0t, Wr0t, Wl1t, Wr1t, Wl2t, Wr2t,
        tmp, nzero);

    // --- CSR build + degree-sorted perm (two-pass counting sort, LDS cursors) ---
    k_count<<<nblkE, TB, 0, stream>>>(tgt, tmp, rank, E);
    k_scanA<<<nscan, TB, 0, stream>>>(tmp, rowptr, bsums, bhist, N);
    k_binit<<<1, 64, 0, stream>>>(bhist, boff, nscan);
    k_scanC<<<nscan, TB, 0, stream>>>(rowptr, bsums, edst, tmp, boff, perm, nscan, N);
    k_scatter<<<nblkE, TB, 0, stream>>>(src, tgt, rank, rowptr, edst, E);

    int gemmBlocks = (N + 63) / 64;
    dim3 gemmGrid2(gemmBlocks, 2);
    dim3 gemmGrid1(gemmBlocks, 1);
    int aggBlocks = (N + 15) / 16;

    // --- layer 0 ---
    k_gemm_mfma<128><<<gemmGrid2, TB, 0, stream>>>(xh, Wl0t, Wr0t, Ah, B, N);
    k_agg<4, 32, _Float16><<<aggBlocks, TB, 0, stream>>>(Ah, B, att0, b0, rowptr, edst, perm, Cbh, N);

    // --- layer 1 ---
    k_gemm_mfma<128><<<gemmGrid2, TB, 0, stream>>>(Cbh, Wl1t, Wr1t, Ah, B, N);
    k_agg<4, 32, _Float16><<<aggBlocks, TB, 0, stream>>>(Ah, B, att1, b1, rowptr, edst, perm, Cbh, N);

    // --- layer 2 ---
    k_gemm_mfma<64><<<gemmGrid1, TB, 0, stream>>>(Cbh, Wl2t, Wr2t, Ah, B, N);
    k_agg<1, 64, float><<<aggBlocks, TB, 0, stream>>>(Ah, B, att2, b2, rowptr, edst, perm, Cbf, N);

    // --- hierarchical global mean pool ---
    dim3 poolGrid(G, 16);
    k_pool_partial<<<poolGrid, TB, 0, stream>>>(Cbf, batch, pacc, N, 16);
    k_pool_final<<<G, 64, 0, stream>>>(pacc, batch, (float*)d_out, N);
}

// Round 15
// 358.363 us; speedup vs baseline: 1.4043x; 1.0605x over previous
//
#include <hip/hip_runtime.h>
#include <hip/hip_fp16.h>
#include <math.h>

#define NEGSLOPE 0.2f

typedef _Float16 f16x8 __attribute__((ext_vector_type(8)));
typedef _Float16 f16x2 __attribute__((ext_vector_type(2)));
typedef float f32x4 __attribute__((ext_vector_type(4)));

__device__ __forceinline__ float lrelu(float x) { return x > 0.f ? x : NEGSLOPE * x; }

__device__ __forceinline__ float dot2acc(f16x2 a, f16x2 b, float c) {
#if __has_builtin(__builtin_amdgcn_fdot2)
    return __builtin_amdgcn_fdot2(a, b, c, false);
#else
    return c + (float)a[0] * (float)b[0] + (float)a[1] * (float)b[1];
#endif
}

// ---------------- prep: zero deg/pacc + x->fp16 + weight transpose -----------
__global__ __launch_bounds__(256) void k_prep(
        const float* __restrict__ x, _Float16* __restrict__ xh, int n8, int XB,
        const float* W0, const float* W1, const float* W2,
        const float* W3, const float* W4, const float* W5,
        _Float16* D0, _Float16* D1, _Float16* D2,
        _Float16* D3, _Float16* D4, _Float16* D5,
        int* __restrict__ zbase, int nzero) {
    int b = blockIdx.x, t = threadIdx.x;
    if (b < XB) {
        int i = b * 256 + t;
        if (i < n8) {
            float4 a = ((const float4*)x)[2 * i], c = ((const float4*)x)[2 * i + 1];
            union { uint4 u; _Float16 h[8]; } pk;
            pk.h[0] = (_Float16)a.x; pk.h[1] = (_Float16)a.y;
            pk.h[2] = (_Float16)a.z; pk.h[3] = (_Float16)a.w;
            pk.h[4] = (_Float16)c.x; pk.h[5] = (_Float16)c.y;
            pk.h[6] = (_Float16)c.z; pk.h[7] = (_Float16)c.w;
            ((uint4*)xh)[i] = pk.u;
        }
    } else if (b < XB + 320) {
        const float* Ws[6] = {W0, W1, W2, W3, W4, W5};
        _Float16* Ds[6] = {D0, D1, D2, D3, D4, D5};
        int j = (b - XB) * 256 + t;
        int m, jj, kout;
        if (j < 65536) { m = j >> 14; jj = j & 16383; kout = 128; }
        else           { m = 4 + ((j - 65536) >> 13); jj = (j - 65536) & 8191; kout = 64; }
        int col = jj >> 7, k = jj & 127;
        Ds[m][col * 128 + k] = (_Float16)Ws[m][k * kout + col];
    } else {
        int i = (b - XB - 320) * 256 + t;
        if (i < nzero) zbase[i] = 0;   // deg + pacc (contiguous)
    }
}

// ---------------- CSR build ----------------
__global__ void k_count(const int* __restrict__ tgt, int* __restrict__ deg,
                        int* __restrict__ rank, int e) {
    int i = blockIdx.x * 256 + threadIdx.x;
    if (i < e) rank[i] = atomicAdd(&deg[tgt[i]], 1);
}
// block scans 4096 elements; +1 folds self-loop; per-block 64-bucket histogram
__global__ __launch_bounds__(256) void k_scanA(const int* __restrict__ deg, int* __restrict__ rowptr,
                                               int* __restrict__ bsums, int* __restrict__ bhist, int n) {
    __shared__ int s[256];
    __shared__ int lh[64];
    int t = threadIdx.x;
    if (t < 64) lh[t] = 0;
    int base = blockIdx.x * 4096 + t * 16;
    int pre[16];
    int sum = 0;
    __syncthreads();
    for (int i = 0; i < 16; ++i) {
        int idx = base + i;
        int v = 0;
        if (idx < n) {
            v = deg[idx] + 1;
            atomicAdd(&lh[v < 63 ? v : 63], 1);   // LDS atomic — cheap
        }
        pre[i] = sum;
        sum += v;
    }
    s[t] = sum;
    __syncthreads();
    for (int off = 1; off < 256; off <<= 1) {
        int v = (t >= off) ? s[t - off] : 0;
        __syncthreads();
        s[t] += v;
        __syncthreads();
    }
    int tbase = s[t] - sum;
    for (int i = 0; i < 16; ++i) {
        int idx = base + i;
        if (idx < n) rowptr[idx] = tbase + pre[i];
    }
    if (t == 0) bsums[blockIdx.x] = s[255];
    if (t < 64) bhist[blockIdx.x * 64 + t] = lh[t];
}
// bucket offsets per scan-block
__global__ void k_binit(const int* __restrict__ bhist, int* __restrict__ boff, int nscan) {
    __shared__ int tots[64];
    __shared__ int base[64];
    int b = threadIdx.x;
    int tot = 0;
    for (int sb = 0; sb < nscan; ++sb) {
        boff[sb * 64 + b] = tot;
        tot += bhist[sb * 64 + b];
    }
    tots[b] = tot;
    __syncthreads();
    if (b == 0) {
        int run = 0;
        for (int k = 0; k < 64; ++k) { base[k] = run; run += tots[k]; }
    }
    __syncthreads();
    for (int sb = 0; sb < nscan; ++sb) boff[sb * 64 + b] += base[b];
}
// finalize rowptr, seed self-loop, build degree-sorted perm via LDS cursors
__global__ __launch_bounds__(256) void k_scanC(int* __restrict__ rowptr, const int* __restrict__ bsums,
                                               int* __restrict__ edst, const int* __restrict__ deg,
                                               const int* __restrict__ boff, int* __restrict__ perm,
                                               int nscan, int n) {
    __shared__ int pref[17];
    __shared__ int cur[64];
    int t = threadIdx.x;
    if (t == 0) {
        int run = 0;
        for (int k = 0; k < nscan; ++k) { pref[k] = run; run += bsums[k]; }
        pref[nscan] = run;
    }
    if (t < 64) cur[t] = boff[blockIdx.x * 64 + t];
    __syncthreads();
    int myoff = pref[blockIdx.x];
    int base = blockIdx.x * 4096 + t * 16;
    for (int i = 0; i < 16; ++i) {
        int idx = base + i;
        if (idx < n) {
            int rp = rowptr[idx] + myoff;
            rowptr[idx] = rp;
            edst[rp] = idx;
            int d = deg[idx] + 1;
            int slot = atomicAdd(&cur[d < 63 ? d : 63], 1);   // LDS atomic
            perm[slot] = idx;
        }
    }
    if (blockIdx.x == gridDim.x - 1 && t == 0) rowptr[n] = pref[nscan];
}
// scatter: no atomics; slot = rowptr[tgt] + 1 + rank
__global__ void k_scatter(const int* __restrict__ src, const int* __restrict__ tgt,
                          const int* __restrict__ rank, const int* __restrict__ rowptr,
                          int* __restrict__ edst, int e) {
    int i = blockIdx.x * 256 + threadIdx.x;
    if (i < e) {
        int p = rowptr[tgt[i]] + 1 + rank[i];
        __builtin_nontemporal_store(src[i], &edst[p]);
    }
}

// ---------------- MFMA fp16 GEMM (swapped operands) --------------------------
// A-operand = weights Wt[KOUT][128] (A[m=lane&15][k=q*8+j] -> contiguous 16B),
// B-operand = activations (B[k=q*8+j][n=lane&15] -> row (row0+m), contiguous 16B).
// D: col=lane&15 -> x-row, row=q*4+reg -> 4 CONSECUTIVE out channels per lane
// -> 8B packed stores. 32 rows/wave (2 B-frag groups share each weight frag set):
// acc[2][8] = 64 VGPRs forces a real multi-frag allocation with hoisted loads.
template<int KOUT>
__global__ __launch_bounds__(256) void k_gemm_mfma(
        const _Float16* __restrict__ Ah,
        const _Float16* __restrict__ Wt0, const _Float16* __restrict__ Wt1,
        _Float16* __restrict__ out0, _Float16* __restrict__ out1, int n) {
    int wv = threadIdx.x >> 6, lane = threadIdx.x & 63;
    int m = lane & 15, q = lane >> 4;
    int row0 = blockIdx.x * 128 + wv * 32;     // 32 rows per wave
    int ra = row0 + m, rb = row0 + 16 + m;
    if (ra >= n) ra = n - 1;
    if (rb >= n) rb = n - 1;
    const _Float16* apa = Ah + (size_t)ra * 128 + q * 8;
    const _Float16* apb = Ah + (size_t)rb * 128 + q * 8;

    const _Float16* Wp = Wt0;
    _Float16* outp = out0;
    if (KOUT == 128 && blockIdx.y) { Wp = Wt1; outp = out1; }

    f32x4 acc0[8] = {}, acc1[8] = {};
#pragma unroll
    for (int kt = 0; kt < 4; ++kt) {
        f16x8 wf[8];
#pragma unroll
        for (int ct = 0; ct < 8; ++ct) {
            const _Float16* W = (KOUT == 128) ? Wp : (ct < 4 ? Wt0 : Wt1);
            int col0 = (KOUT == 128) ? ct * 16 : (ct & 3) * 16;
            wf[ct] = *(const f16x8*)(W + (size_t)(col0 + m) * 128 + 32 * kt + 8 * q);
        }
        f16x8 bf0 = *(const f16x8*)(apa + 32 * kt);
        f16x8 bf1 = *(const f16x8*)(apb + 32 * kt);
#pragma unroll
        for (int ct = 0; ct < 8; ++ct) {
            acc0[ct] = __builtin_amdgcn_mfma_f32_16x16x32_f16(wf[ct], bf0, acc0[ct], 0, 0, 0);
            acc1[ct] = __builtin_amdgcn_mfma_f32_16x16x32_f16(wf[ct], bf1, acc1[ct], 0, 0, 0);
        }
    }
    // stores: lane holds out[x-row][4 consecutive channels q*4..q*4+3] per ct
    int rowa = row0 + m, rowb = row0 + 16 + m;
#pragma unroll
    for (int ct = 0; ct < 8; ++ct) {
        _Float16* dst = (KOUT == 128) ? outp : (ct < 4 ? out0 : out1);
        int col = ((KOUT == 128) ? ct * 16 : (ct & 3) * 16) + q * 4;
        union { uint2 u; _Float16 h[4]; } pk;
        if (rowa < n) {
#pragma unroll
            for (int i = 0; i < 4; ++i) pk.h[i] = (_Float16)acc0[ct][i];
            *(uint2*)(dst + (size_t)rowa * KOUT + col) = pk.u;
        }
        if (rowb < n) {
#pragma unroll
            for (int i = 0; i < 4; ++i) pk.h[i] = (_Float16)acc1[ct][i];
            *(uint2*)(dst + (size_t)rowb * KOUT + col) = pk.u;
        }
    }
}

// ---------------- GATv2 aggregation: 4 nodes/wave, 16 lanes/node --------------
template<int H, int C, typename OutT>
__global__ __launch_bounds__(256) void k_agg(const _Float16* __restrict__ xl, const _Float16* __restrict__ xr,
                                             const float* __restrict__ att, const float* __restrict__ bias,
                                             const int* __restrict__ rowptr, const int* __restrict__ edst,
                                             const int* __restrict__ perm,
                                             OutT* __restrict__ yout, int n) {
    constexpr int F = H * C;
    constexpr int VEC = F / 16;
    constexpr int NH2 = VEC / 2;
    constexpr int L = C / VEC;
    int lane = threadIdx.x & 63;
    int wave = threadIdx.x >> 6;
    int s = lane & 15;
    int gid = blockIdx.x * 16 + wave * 4 + (lane >> 4);
    bool valid = gid < n;
    int node = valid ? perm[gid] : 0;
    int ch = s * VEC;

    f16x2 u2[NH2], av2[NH2];
    {
        union { uint4 u4; uint2 u2v; f16x2 h[4]; } pk;
        if constexpr (NH2 == 4) pk.u4 = *(const uint4*)(xr + (size_t)node * F + ch);
        else pk.u2v = *(const uint2*)(xr + (size_t)node * F + ch);
#pragma unroll
        for (int j = 0; j < NH2; ++j) u2[j] = pk.h[j];
    }
#pragma unroll
    for (int j = 0; j < NH2; ++j) {
        av2[j][0] = (_Float16)att[ch + 2 * j];
        av2[j][1] = (_Float16)att[ch + 2 * j + 1];
    }

    float acc[VEC];
#pragma unroll
    for (int j = 0; j < VEC; ++j) acc[j] = 0.f;
    int e0 = rowptr[node];
    int deg = valid ? (rowptr[node + 1] - e0) : 0;
    int maxdeg = deg;
    maxdeg = max(maxdeg, __shfl_xor(maxdeg, 16));
    maxdeg = max(maxdeg, __shfl_xor(maxdeg, 32));
    float ssum = 0.f;

    const _Float16 cneg = (_Float16)NEGSLOPE;
    auto edge = [&](int srcRow, bool live) {
        union { uint4 u4; uint2 u2v; f16x2 hh[4]; } pk;
        const _Float16* p = xl + (size_t)srcRow * F + ch;
        if constexpr (NH2 == 4) pk.u4 = *(const uint4*)p;
        else pk.u2v = *(const uint2*)p;
        float sc = 0.f;
#pragma unroll
        for (int j = 0; j < NH2; ++j) {
            f16x2 t = pk.hh[j] + u2[j];
            f16x2 lr = __builtin_elementwise_max(t, t * cneg);
            sc = dot2acc(lr, av2[j], sc);
        }
#pragma unroll
        for (int off = 1; off < L; off <<= 1) sc += __shfl_xor(sc, off);
        float w = live ? __expf(sc) : 0.f;
        ssum += w;
#pragma unroll
        for (int j = 0; j < NH2; ++j) {
            acc[2 * j]     += w * (float)pk.hh[j][0];
            acc[2 * j + 1] += w * (float)pk.hh[j][1];
        }
    };

    for (int base = 0; base < maxdeg; base += 16) {
        int cnt = deg - base;
        if (cnt > 16) cnt = 16;
        int idxreg = (s < cnt) ? edst[e0 + base + s] : node;
        int mcnt = cnt;
        mcnt = max(mcnt, __shfl_xor(mcnt, 16));
        mcnt = max(mcnt, __shfl_xor(mcnt, 32));
        int gbase = lane & 48;
        int i = 0;
        for (; i + 2 <= mcnt; i += 2) {
            int s0 = __shfl(idxreg, gbase + i);
            int s1 = __shfl(idxreg, gbase + i + 1);
            edge(s0, i < cnt);
            edge(s1, i + 1 < cnt);
        }
        for (; i < mcnt; ++i) {
            int s0 = __shfl(idxreg, gbase + i);
            edge(s0, i < cnt);
        }
    }
    if (valid) {
        float inv = 1.f / ssum;
        float o[VEC];
#pragma unroll
        for (int j = 0; j < VEC; ++j) o[j] = lrelu(acc[j] * inv + bias[ch + j]);
        if constexpr (sizeof(OutT) == 2) {
            _Float16* p = (_Float16*)yout + (size_t)node * F + ch;
            if constexpr (VEC == 8) {
                union { uint4 u; _Float16 h[8]; } pk;
#pragma unroll
                for (int j = 0; j < 8; ++j) pk.h[j] = (_Float16)o[j];
                *(uint4*)p = pk.u;
            } else {
                union { uint2 u; _Float16 h[4]; } pk;
#pragma unroll
                for (int j = 0; j < 4; ++j) pk.h[j] = (_Float16)o[j];
                *(uint2*)p = pk.u;
            }
        } else {
            float* p = (float*)yout + (size_t)node * F + ch;
            *(float4*)p = make_float4(o[0], o[1], o[2], o[3]);
            if constexpr (VEC == 8)
                *(float4*)(p + 4) = make_float4(o[4], o[5], o[6], o[7]);
        }
    }
}

// ---------------- hierarchical global mean pool ----------------
__global__ __launch_bounds__(256) void k_pool_partial(const float* __restrict__ y,
        const int* __restrict__ batch, float* __restrict__ pacc, int n, int nchunk) {
    __shared__ float sdata[256];
    __shared__ int range[2];
    int g = blockIdx.x;
    int chunk = blockIdx.y;
    int t = threadIdx.x;
    if (t == 0) {
        int lo = 0, hi = n;
        while (lo < hi) { int mid = (lo + hi) >> 1; if (batch[mid] < g) lo = mid + 1; else hi = mid; }
        range[0] = lo;
        hi = n;
        while (lo < hi) { int mid = (lo + hi) >> 1; if (batch[mid] < g + 1) lo = mid + 1; else hi = mid; }
        range[1] = lo;
    }
    __syncthreads();
    int start = range[0], len = range[1] - range[0];
    int lo = start + (int)((long long)len * chunk / nchunk);
    int hi = start + (int)((long long)len * (chunk + 1) / nchunk);
    int ch = t & 63, sub = t >> 6;
    float acc = 0.f;
    for (int node = lo + sub; node < hi; node += 4)
        acc += y[(size_t)node * 64 + ch];
    sdata[t] = acc;
    __syncthreads();
    if (t < 128) sdata[t] += sdata[t + 128];
    __syncthreads();
    if (t < 64) atomicAdd(&pacc[g * 64 + t], sdata[t] + sdata[t + 64]);
}
__global__ void k_pool_final(const float* __restrict__ pacc, const int* __restrict__ batch,
                             float* __restrict__ out, int n) {
    __shared__ int cntS;
    int g = blockIdx.x, t = threadIdx.x;
    if (t == 0) {
        int lo = 0, hi = n;
        while (lo < hi) { int mid = (lo + hi) >> 1; if (batch[mid] < g) lo = mid + 1; else hi = mid; }
        int s = lo;
        hi = n;
        while (lo < hi) { int mid = (lo + hi) >> 1; if (batch[mid] < g + 1) lo = mid + 1; else hi = mid; }
        cntS = lo - s;
    }
    __syncthreads();
    out[g * 64 + t] = pacc[g * 64 + t] / fmaxf((float)cntS, 1.f);
}

extern "C" void kernel_launch(void* const* d_in, const int* in_sizes, int n_in,
                              void* d_out, int out_size, void* d_ws, size_t ws_size,
                              hipStream_t stream) {
    const float* x     = (const float*)d_in[0];
    const int*   ei    = (const int*)d_in[1];
    const int*   batch = (const int*)d_in[2];
    const float* Wl0 = (const float*)d_in[3];
    const float* Wr0 = (const float*)d_in[4];
    const float* att0 = (const float*)d_in[5];
    const float* b0  = (const float*)d_in[6];
    const float* Wl1 = (const float*)d_in[7];
    const float* Wr1 = (const float*)d_in[8];
    const float* att1 = (const float*)d_in[9];
    const float* b1  = (const float*)d_in[10];
    const float* Wl2 = (const float*)d_in[11];
    const float* Wr2 = (const float*)d_in[12];
    const float* att2 = (const float*)d_in[13];
    const float* b2  = (const float*)d_in[14];

    const int N = in_sizes[2];        // 50000
    const int E = in_sizes[1] / 2;    // 800000
    const int G = out_size / 64;      // 64
    const int* src = ei;
    const int* tgt = ei + E;

    size_t off = 0;
    auto take = [&](size_t bytes) {
        void* p = (char*)d_ws + off;
        off = (off + bytes + 255) & ~(size_t)255;
        return p;
    };
    _Float16* xh   = (_Float16*)take((size_t)N * 128 * 2);
    _Float16* Ah   = (_Float16*)take((size_t)N * 128 * 2); // xl
    _Float16* B    = (_Float16*)take((size_t)N * 128 * 2); // xr
    _Float16* Cbh  = (_Float16*)take((size_t)N * 128 * 2); // agg out layers 0/1
    float* Cbf     = (float*)take((size_t)N * 64 * 4);     // agg out layer 2
    _Float16* Wl0t = (_Float16*)take(128 * 128 * 2);
    _Float16* Wr0t = (_Float16*)take(128 * 128 * 2);
    _Float16* Wl1t = (_Float16*)take(128 * 128 * 2);
    _Float16* Wr1t = (_Float16*)take(128 * 128 * 2);
    _Float16* Wl2t = (_Float16*)take(64 * 128 * 2);
    _Float16* Wr2t = (_Float16*)take(64 * 128 * 2);
    int* rowptr = (int*)take((size_t)(N + 1) * 4);
    // contiguous zero region: deg(N) + pacc(G*64)
    int* tmp    = (int*)take((size_t)N * 4);
    float* pacc = (float*)take((size_t)G * 64 * 4);
    int* bhist  = (int*)take(16 * 64 * 4);
    int* boff   = (int*)take(16 * 64 * 4);
    int* perm   = (int*)take((size_t)N * 4);
    int* rank   = (int*)take((size_t)E * 4);
    int* edst   = (int*)take((size_t)(E + N) * 4);
    int* bsums  = (int*)take(64 * 4);
    (void)ws_size; (void)n_in;

    const int TB = 256;
    int nblkE = (E + TB - 1) / TB;
    int nscan = (N + 4095) / 4096;

    // --- prep: zeroing + fp16 conversions (one launch) ---
    int n8 = N * 128 / 8;
    int XB = (n8 + TB - 1) / TB;
    int nzero = (int)(((char*)bhist) - (char*)tmp) / 4;
    int ZB = (nzero + TB - 1) / TB;
    k_prep<<<XB + 320 + ZB, TB, 0, stream>>>(x, xh, n8, XB,
        Wl0, Wr0, Wl1, Wr1, Wl2, Wr2,
        Wl0t, Wr0t, Wl1t, Wr1t, Wl2t, Wr2t,
        tmp, nzero);

    // --- CSR build + degree-sorted perm (two-pass counting sort, LDS cursors) ---
    k_count<<<nblkE, TB, 0, stream>>>(tgt, tmp, rank, E);
    k_scanA<<<nscan, TB, 0, stream>>>(tmp, rowptr, bsums, bhist, N);
    k_binit<<<1, 64, 0, stream>>>(bhist, boff, nscan);
    k_scanC<<<nscan, TB, 0, stream>>>(rowptr, bsums, edst, tmp, boff, perm, nscan, N);
    k_scatter<<<nblkE, TB, 0, stream>>>(src, tgt, rank, rowptr, edst, E);

    int gemmBlocks = (N + 127) / 128;     // 128 rows/block (32 per wave)
    dim3 gemmGrid2(gemmBlocks, 2);
    dim3 gemmGrid1(gemmBlocks, 1);
    int aggBlocks = (N + 15) / 16;

    // --- layer 0 ---
    k_gemm_mfma<128><<<gemmGrid2, TB, 0, stream>>>(xh, Wl0t, Wr0t, Ah, B, N);
    k_agg<4, 32, _Float16><<<aggBlocks, TB, 0, stream>>>(Ah, B, att0, b0, rowptr, edst, perm, Cbh, N);

    // --- layer 1 ---
    k_gemm_mfma<128><<<gemmGrid2, TB, 0, stream>>>(Cbh, Wl1t, Wr1t, Ah, B, N);
    k_agg<4, 32, _Float16><<<aggBlocks, TB, 0, stream>>>(Ah, B, att1, b1, rowptr, edst, perm, Cbh, N);

    // --- layer 2 ---
    k_gemm_mfma<64><<<gemmGrid1, TB, 0, stream>>>(Cbh, Wl2t, Wr2t, Ah, B, N);
    k_agg<1, 64, float><<<aggBlocks, TB, 0, stream>>>(Ah, B, att2, b2, rowptr, edst, perm, Cbf, N);

    // --- hierarchical global mean pool ---
    dim3 poolGrid(G, 16);
    k_pool_partial<<<poolGrid, TB, 0, stream>>>(Cbf, batch, pacc, N, 16);
    k_pool_final<<<G, 64, 0, stream>>>(pacc, batch, (float*)d_out, N);
}

// Round 16
// 357.262 us; speedup vs baseline: 1.4086x; 1.0031x over previous
//
#include <hip/hip_runtime.h>
#include <hip/hip_fp16.h>
#include <math.h>

#define NEGSLOPE 0.2f

typedef _Float16 f16x8 __attribute__((ext_vector_type(8)));
typedef _Float16 f16x2 __attribute__((ext_vector_type(2)));
typedef float f32x4 __attribute__((ext_vector_type(4)));

__device__ __forceinline__ float lrelu(float x) { return x > 0.f ? x : NEGSLOPE * x; }

__device__ __forceinline__ float dot2acc(f16x2 a, f16x2 b, float c) {
#if __has_builtin(__builtin_amdgcn_fdot2)
    return __builtin_amdgcn_fdot2(a, b, c, false);
#else
    return c + (float)a[0] * (float)b[0] + (float)a[1] * (float)b[1];
#endif
}

// ---------------- prep: zero deg/pacc + weight transpose->fp16 ---------------
__global__ __launch_bounds__(256) void k_prep(
        const float* W0, const float* W1, const float* W2,
        const float* W3, const float* W4, const float* W5,
        _Float16* D0, _Float16* D1, _Float16* D2,
        _Float16* D3, _Float16* D4, _Float16* D5,
        int* __restrict__ zbase, int nzero) {
    int b = blockIdx.x, t = threadIdx.x;
    if (b < 320) {
        const float* Ws[6] = {W0, W1, W2, W3, W4, W5};
        _Float16* Ds[6] = {D0, D1, D2, D3, D4, D5};
        int j = b * 256 + t;
        int m, jj, kout;
        if (j < 65536) { m = j >> 14; jj = j & 16383; kout = 128; }
        else           { m = 4 + ((j - 65536) >> 13); jj = (j - 65536) & 8191; kout = 64; }
        int col = jj >> 7, k = jj & 127;
        Ds[m][col * 128 + k] = (_Float16)Ws[m][k * kout + col];
    } else {
        int i = (b - 320) * 256 + t;
        if (i < nzero) zbase[i] = 0;   // deg + pacc (contiguous)
    }
}

// ---------------- CSR build ----------------
__global__ void k_count(const int* __restrict__ tgt, int* __restrict__ deg,
                        int* __restrict__ rank, int e) {
    int i = blockIdx.x * 256 + threadIdx.x;
    if (i < e) rank[i] = atomicAdd(&deg[tgt[i]], 1);
}
// block scans 4096 elements; +1 folds self-loop; per-block 64-bucket histogram
__global__ __launch_bounds__(256) void k_scanA(const int* __restrict__ deg, int* __restrict__ rowptr,
                                               int* __restrict__ bsums, int* __restrict__ bhist, int n) {
    __shared__ int s[256];
    __shared__ int lh[64];
    int t = threadIdx.x;
    if (t < 64) lh[t] = 0;
    int base = blockIdx.x * 4096 + t * 16;
    int pre[16];
    int sum = 0;
    __syncthreads();
    for (int i = 0; i < 16; ++i) {
        int idx = base + i;
        int v = 0;
        if (idx < n) {
            v = deg[idx] + 1;
            atomicAdd(&lh[v < 63 ? v : 63], 1);   // LDS atomic — cheap
        }
        pre[i] = sum;
        sum += v;
    }
    s[t] = sum;
    __syncthreads();
    for (int off = 1; off < 256; off <<= 1) {
        int v = (t >= off) ? s[t - off] : 0;
        __syncthreads();
        s[t] += v;
        __syncthreads();
    }
    int tbase = s[t] - sum;
    for (int i = 0; i < 16; ++i) {
        int idx = base + i;
        if (idx < n) rowptr[idx] = tbase + pre[i];
    }
    if (t == 0) bsums[blockIdx.x] = s[255];
    if (t < 64) bhist[blockIdx.x * 64 + t] = lh[t];
}
// finalize rowptr, seed self-loop, build degree-sorted perm via LDS cursors.
// Bucket offsets recomputed per block from bhist (binit folded in — 4KB read).
__global__ __launch_bounds__(256) void k_scanC(int* __restrict__ rowptr, const int* __restrict__ bsums,
                                               int* __restrict__ edst, const int* __restrict__ deg,
                                               const int* __restrict__ bhist, int* __restrict__ perm,
                                               int nscan, int n) {
    __shared__ int pref[17];
    __shared__ int cur[64];
    __shared__ int bbase[64];
    int t = threadIdx.x;
    if (t == 0) {
        int run = 0;
        for (int k = 0; k < nscan; ++k) { pref[k] = run; run += bsums[k]; }
        pref[nscan] = run;
    }
    if (t < 64) {
        int part = 0, tot = 0;
        for (int sb = 0; sb < nscan; ++sb) {
            int v = bhist[sb * 64 + t];
            if (sb < (int)blockIdx.x) part += v;
            tot += v;
        }
        bbase[t] = tot;      // temporarily totals
        cur[t] = part;
    }
    __syncthreads();
    if (t == 0) {
        int run = 0;
        for (int k = 0; k < 64; ++k) { int v = bbase[k]; bbase[k] = run; run += v; }
    }
    __syncthreads();
    if (t < 64) cur[t] += bbase[t];
    __syncthreads();
    int myoff = pref[blockIdx.x];
    int base = blockIdx.x * 4096 + t * 16;
    for (int i = 0; i < 16; ++i) {
        int idx = base + i;
        if (idx < n) {
            int rp = rowptr[idx] + myoff;
            rowptr[idx] = rp;
            edst[rp] = idx;
            int d = deg[idx] + 1;
            int slot = atomicAdd(&cur[d < 63 ? d : 63], 1);   // LDS atomic
            perm[slot] = idx;
        }
    }
    if (blockIdx.x == gridDim.x - 1 && t == 0) rowptr[n] = pref[nscan];
}
// scatter: no atomics; slot = rowptr[tgt] + 1 + rank
__global__ void k_scatter(const int* __restrict__ src, const int* __restrict__ tgt,
                          const int* __restrict__ rank, const int* __restrict__ rowptr,
                          int* __restrict__ edst, int e) {
    int i = blockIdx.x * 256 + threadIdx.x;
    if (i < e) {
        int p = rowptr[tgt[i]] + 1 + rank[i];
        __builtin_nontemporal_store(src[i], &edst[p]);
    }
}

// ---------------- MFMA fp16 GEMM (swapped operands) --------------------------
// A-operand = weights Wt[KOUT][128]; B-operand = activation rows (AT = f16 or
// f32 — f32 is converted in-register, the kernel is latency-bound so cvts are
// free). D: col=lane&15 -> x-row, row=q*4+reg -> 4 consecutive out channels
// -> 8B packed stores. 32 rows/wave: acc[2][8]=64 VGPRs, hoisted frag loads.
template<int KOUT, typename AT>
__global__ __launch_bounds__(256) void k_gemm_mfma(
        const AT* __restrict__ Ah,
        const _Float16* __restrict__ Wt0, const _Float16* __restrict__ Wt1,
        _Float16* __restrict__ out0, _Float16* __restrict__ out1, int n) {
    int wv = threadIdx.x >> 6, lane = threadIdx.x & 63;
    int m = lane & 15, q = lane >> 4;
    int row0 = blockIdx.x * 128 + wv * 32;     // 32 rows per wave
    int ra = row0 + m, rb = row0 + 16 + m;
    if (ra >= n) ra = n - 1;
    if (rb >= n) rb = n - 1;
    const AT* apa = Ah + (size_t)ra * 128 + q * 8;
    const AT* apb = Ah + (size_t)rb * 128 + q * 8;

    auto loadB = [](const AT* p) -> f16x8 {
        if constexpr (sizeof(AT) == 2) {
            return *(const f16x8*)p;
        } else {
            float4 a = *(const float4*)p, b = *(const float4*)(p + 4);
            f16x8 r;
            r[0] = (_Float16)a.x; r[1] = (_Float16)a.y; r[2] = (_Float16)a.z; r[3] = (_Float16)a.w;
            r[4] = (_Float16)b.x; r[5] = (_Float16)b.y; r[6] = (_Float16)b.z; r[7] = (_Float16)b.w;
            return r;
        }
    };

    const _Float16* Wp = Wt0;
    _Float16* outp = out0;
    if (KOUT == 128 && blockIdx.y) { Wp = Wt1; outp = out1; }

    f32x4 acc0[8] = {}, acc1[8] = {};
#pragma unroll
    for (int kt = 0; kt < 4; ++kt) {
        f16x8 wf[8];
#pragma unroll
        for (int ct = 0; ct < 8; ++ct) {
            const _Float16* W = (KOUT == 128) ? Wp : (ct < 4 ? Wt0 : Wt1);
            int col0 = (KOUT == 128) ? ct * 16 : (ct & 3) * 16;
            wf[ct] = *(const f16x8*)(W + (size_t)(col0 + m) * 128 + 32 * kt + 8 * q);
        }
        f16x8 bf0 = loadB(apa + 32 * kt);
        f16x8 bf1 = loadB(apb + 32 * kt);
#pragma unroll
        for (int ct = 0; ct < 8; ++ct) {
            acc0[ct] = __builtin_amdgcn_mfma_f32_16x16x32_f16(wf[ct], bf0, acc0[ct], 0, 0, 0);
            acc1[ct] = __builtin_amdgcn_mfma_f32_16x16x32_f16(wf[ct], bf1, acc1[ct], 0, 0, 0);
        }
    }
    int rowa = row0 + m, rowb = row0 + 16 + m;
#pragma unroll
    for (int ct = 0; ct < 8; ++ct) {
        _Float16* dst = (KOUT == 128) ? outp : (ct < 4 ? out0 : out1);
        int col = ((KOUT == 128) ? ct * 16 : (ct & 3) * 16) + q * 4;
        union { uint2 u; _Float16 h[4]; } pk;
        if (rowa < n) {
#pragma unroll
            for (int i = 0; i < 4; ++i) pk.h[i] = (_Float16)acc0[ct][i];
            *(uint2*)(dst + (size_t)rowa * KOUT + col) = pk.u;
        }
        if (rowb < n) {
#pragma unroll
            for (int i = 0; i < 4; ++i) pk.h[i] = (_Float16)acc1[ct][i];
            *(uint2*)(dst + (size_t)rowb * KOUT + col) = pk.u;
        }
    }
}

// ---------------- GATv2 aggregation: 4 nodes/wave, 16 lanes/node --------------
// Degree-sorted perm; packed-f16 score path; f32 accumulate. Edge loop x4 with
// explicit load-phase/compute-phase split: 16 gathers in flight per wave.
template<int H, int C, typename OutT>
__global__ __launch_bounds__(256) void k_agg(const _Float16* __restrict__ xl, const _Float16* __restrict__ xr,
                                             const float* __restrict__ att, const float* __restrict__ bias,
                                             const int* __restrict__ rowptr, const int* __restrict__ edst,
                                             const int* __restrict__ perm,
                                             OutT* __restrict__ yout, int n) {
    constexpr int F = H * C;
    constexpr int VEC = F / 16;
    constexpr int NH2 = VEC / 2;
    constexpr int L = C / VEC;
    int lane = threadIdx.x & 63;
    int wave = threadIdx.x >> 6;
    int s = lane & 15;
    int gid = blockIdx.x * 16 + wave * 4 + (lane >> 4);
    bool valid = gid < n;
    int node = valid ? perm[gid] : 0;
    int ch = s * VEC;

    union PkU { uint4 u4; uint2 u2v; f16x2 hh[4]; };

    f16x2 u2[NH2], av2[NH2];
    {
        PkU pk;
        if constexpr (NH2 == 4) pk.u4 = *(const uint4*)(xr + (size_t)node * F + ch);
        else pk.u2v = *(const uint2*)(xr + (size_t)node * F + ch);
#pragma unroll
        for (int j = 0; j < NH2; ++j) u2[j] = pk.hh[j];
    }
#pragma unroll
    for (int j = 0; j < NH2; ++j) {
        av2[j][0] = (_Float16)att[ch + 2 * j];
        av2[j][1] = (_Float16)att[ch + 2 * j + 1];
    }

    float acc[VEC];
#pragma unroll
    for (int j = 0; j < VEC; ++j) acc[j] = 0.f;
    int e0 = rowptr[node];
    int deg = valid ? (rowptr[node + 1] - e0) : 0;
    int maxdeg = deg;
    maxdeg = max(maxdeg, __shfl_xor(maxdeg, 16));
    maxdeg = max(maxdeg, __shfl_xor(maxdeg, 32));
    float ssum = 0.f;

    const _Float16 cneg = (_Float16)NEGSLOPE;
    auto loadrow = [&](int srcRow, PkU& pk) {
        const _Float16* p = xl + (size_t)srcRow * F + ch;
        if constexpr (NH2 == 4) pk.u4 = *(const uint4*)p;
        else pk.u2v = *(const uint2*)p;
    };
    auto process = [&](PkU& pk, bool live) {
        float sc = 0.f;
#pragma unroll
        for (int j = 0; j < NH2; ++j) {
            f16x2 t = pk.hh[j] + u2[j];
            f16x2 lr = __builtin_elementwise_max(t, t * cneg);
            sc = dot2acc(lr, av2[j], sc);
        }
#pragma unroll
        for (int off = 1; off < L; off <<= 1) sc += __shfl_xor(sc, off);
        float w = live ? __expf(sc) : 0.f;
        ssum += w;
#pragma unroll
        for (int j = 0; j < NH2; ++j) {
            acc[2 * j]     += w * (float)pk.hh[j][0];
            acc[2 * j + 1] += w * (float)pk.hh[j][1];
        }
    };

    for (int base = 0; base < maxdeg; base += 16) {
        int cnt = deg - base;
        if (cnt > 16) cnt = 16;
        int idxreg = (s < cnt) ? edst[e0 + base + s] : node;
        int mcnt = cnt;
        mcnt = max(mcnt, __shfl_xor(mcnt, 16));
        mcnt = max(mcnt, __shfl_xor(mcnt, 32));
        int gbase = lane & 48;
        int i = 0;
        for (; i + 4 <= mcnt; i += 4) {
            int s0 = __shfl(idxreg, gbase + i);
            int s1 = __shfl(idxreg, gbase + i + 1);
            int s2 = __shfl(idxreg, gbase + i + 2);
            int s3 = __shfl(idxreg, gbase + i + 3);
            PkU p0, p1, p2, p3;
            loadrow(s0, p0); loadrow(s1, p1); loadrow(s2, p2); loadrow(s3, p3);
            process(p0, i < cnt);
            process(p1, i + 1 < cnt);
            process(p2, i + 2 < cnt);
            process(p3, i + 3 < cnt);
        }
        for (; i < mcnt; ++i) {
            int s0 = __shfl(idxreg, gbase + i);
            PkU p0;
            loadrow(s0, p0);
            process(p0, i < cnt);
        }
    }
    if (valid) {
        float inv = 1.f / ssum;
        float o[VEC];
#pragma unroll
        for (int j = 0; j < VEC; ++j) o[j] = lrelu(acc[j] * inv + bias[ch + j]);
        if constexpr (sizeof(OutT) == 2) {
            _Float16* p = (_Float16*)yout + (size_t)node * F + ch;
            if constexpr (VEC == 8) {
                union { uint4 u; _Float16 h[8]; } pk;
#pragma unroll
                for (int j = 0; j < 8; ++j) pk.h[j] = (_Float16)o[j];
                *(uint4*)p = pk.u;
            } else {
                union { uint2 u; _Float16 h[4]; } pk;
#pragma unroll
                for (int j = 0; j < 4; ++j) pk.h[j] = (_Float16)o[j];
                *(uint2*)p = pk.u;
            }
        } else {
            float* p = (float*)yout + (size_t)node * F + ch;
            *(float4*)p = make_float4(o[0], o[1], o[2], o[3]);
            if constexpr (VEC == 8)
                *(float4*)(p + 4) = make_float4(o[4], o[5], o[6], o[7]);
        }
    }
}

// ---------------- hierarchical global mean pool ----------------
__global__ __launch_bounds__(256) void k_pool_partial(const float* __restrict__ y,
        const int* __restrict__ batch, float* __restrict__ pacc, int n, int nchunk) {
    __shared__ float sdata[256];
    __shared__ int range[2];
    int g = blockIdx.x;
    int chunk = blockIdx.y;
    int t = threadIdx.x;
    if (t == 0) {
        int lo = 0, hi = n;
        while (lo < hi) { int mid = (lo + hi) >> 1; if (batch[mid] < g) lo = mid + 1; else hi = mid; }
        range[0] = lo;
        hi = n;
        while (lo < hi) { int mid = (lo + hi) >> 1; if (batch[mid] < g + 1) lo = mid + 1; else hi = mid; }
        range[1] = lo;
    }
    __syncthreads();
    int start = range[0], len = range[1] - range[0];
    int lo = start + (int)((long long)len * chunk / nchunk);
    int hi = start + (int)((long long)len * (chunk + 1) / nchunk);
    int ch = t & 63, sub = t >> 6;
    float acc = 0.f;
    for (int node = lo + sub; node < hi; node += 4)
        acc += y[(size_t)node * 64 + ch];
    sdata[t] = acc;
    __syncthreads();
    if (t < 128) sdata[t] += sdata[t + 128];
    __syncthreads();
    if (t < 64) atomicAdd(&pacc[g * 64 + t], sdata[t] + sdata[t + 64]);
}
__global__ void k_pool_final(const float* __restrict__ pacc, const int* __restrict__ batch,
                             float* __restrict__ out, int n) {
    __shared__ int cntS;
    int g = blockIdx.x, t = threadIdx.x;
    if (t == 0) {
        int lo = 0, hi = n;
        while (lo < hi) { int mid = (lo + hi) >> 1; if (batch[mid] < g) lo = mid + 1; else hi = mid; }
        int s = lo;
        hi = n;
        while (lo < hi) { int mid = (lo + hi) >> 1; if (batch[mid] < g + 1) lo = mid + 1; else hi = mid; }
        cntS = lo - s;
    }
    __syncthreads();
    out[g * 64 + t] = pacc[g * 64 + t] / fmaxf((float)cntS, 1.f);
}

extern "C" void kernel_launch(void* const* d_in, const int* in_sizes, int n_in,
                              void* d_out, int out_size, void* d_ws, size_t ws_size,
                              hipStream_t stream) {
    const float* x     = (const float*)d_in[0];
    const int*   ei    = (const int*)d_in[1];
    const int*   batch = (const int*)d_in[2];
    const float* Wl0 = (const float*)d_in[3];
    const float* Wr0 = (const float*)d_in[4];
    const float* att0 = (const float*)d_in[5];
    const float* b0  = (const float*)d_in[6];
    const float* Wl1 = (const float*)d_in[7];
    const float* Wr1 = (const float*)d_in[8];
    const float* att1 = (const float*)d_in[9];
    const float* b1  = (const float*)d_in[10];
    const float* Wl2 = (const float*)d_in[11];
    const float* Wr2 = (const float*)d_in[12];
    const float* att2 = (const float*)d_in[13];
    const float* b2  = (const float*)d_in[14];

    const int N = in_sizes[2];        // 50000
    const int E = in_sizes[1] / 2;    // 800000
    const int G = out_size / 64;      // 64
    const int* src = ei;
    const int* tgt = ei + E;

    size_t off = 0;
    auto take = [&](size_t bytes) {
        void* p = (char*)d_ws + off;
        off = (off + bytes + 255) & ~(size_t)255;
        return p;
    };
    _Float16* Ah   = (_Float16*)take((size_t)N * 128 * 2); // xl
    _Float16* B    = (_Float16*)take((size_t)N * 128 * 2); // xr
    _Float16* Cbh  = (_Float16*)take((size_t)N * 128 * 2); // agg out layers 0/1
    float* Cbf     = (float*)take((size_t)N * 64 * 4);     // agg out layer 2
    _Float16* Wl0t = (_Float16*)take(128 * 128 * 2);
    _Float16* Wr0t = (_Float16*)take(128 * 128 * 2);
    _Float16* Wl1t = (_Float16*)take(128 * 128 * 2);
    _Float16* Wr1t = (_Float16*)take(128 * 128 * 2);
    _Float16* Wl2t = (_Float16*)take(64 * 128 * 2);
    _Float16* Wr2t = (_Float16*)take(64 * 128 * 2);
    int* rowptr = (int*)take((size_t)(N + 1) * 4);
    // contiguous zero region: deg(N) + pacc(G*64)
    int* tmp    = (int*)take((size_t)N * 4);
    float* pacc = (float*)take((size_t)G * 64 * 4);
    int* bhist  = (int*)take(16 * 64 * 4);
    int* perm   = (int*)take((size_t)N * 4);
    int* rank   = (int*)take((size_t)E * 4);
    int* edst   = (int*)take((size_t)(E + N) * 4);
    int* bsums  = (int*)take(64 * 4);
    (void)ws_size; (void)n_in;

    const int TB = 256;
    int nblkE = (E + TB - 1) / TB;
    int nscan = (N + 4095) / 4096;

    // --- prep: zeroing + weight transpose (one launch) ---
    int nzero = (int)(((char*)bhist) - (char*)tmp) / 4;
    int ZB = (nzero + TB - 1) / TB;
    k_prep<<<320 + ZB, TB, 0, stream>>>(
        Wl0, Wr0, Wl1, Wr1, Wl2, Wr2,
        Wl0t, Wr0t, Wl1t, Wr1t, Wl2t, Wr2t,
        tmp, nzero);

    // --- CSR build + degree-sorted perm (two-pass counting sort, LDS cursors) ---
    k_count<<<nblkE, TB, 0, stream>>>(tgt, tmp, rank, E);
    k_scanA<<<nscan, TB, 0, stream>>>(tmp, rowptr, bsums, bhist, N);
    k_scanC<<<nscan, TB, 0, stream>>>(rowptr, bsums, edst, tmp, bhist, perm, nscan, N);
    k_scatter<<<nblkE, TB, 0, stream>>>(src, tgt, rank, rowptr, edst, E);

    int gemmBlocks = (N + 127) / 128;     // 128 rows/block (32 per wave)
    dim3 gemmGrid2(gemmBlocks, 2);
    dim3 gemmGrid1(gemmBlocks, 1);
    int aggBlocks = (N + 15) / 16;

    // --- layer 0 (reads fp32 x directly, converts in-register) ---
    k_gemm_mfma<128, float><<<gemmGrid2, TB, 0, stream>>>(x, Wl0t, Wr0t, Ah, B, N);
    k_agg<4, 32, _Float16><<<aggBlocks, TB, 0, stream>>>(Ah, B, att0, b0, rowptr, edst, perm, Cbh, N);

    // --- layer 1 ---
    k_gemm_mfma<128, _Float16><<<gemmGrid2, TB, 0, stream>>>(Cbh, Wl1t, Wr1t, Ah, B, N);
    k_agg<4, 32, _Float16><<<aggBlocks, TB, 0, stream>>>(Ah, B, att1, b1, rowptr, edst, perm, Cbh, N);

    // --- layer 2 ---
    k_gemm_mfma<64, _Float16><<<gemmGrid1, TB, 0, stream>>>(Cbh, Wl2t, Wr2t, Ah, B, N);
    k_agg<1, 64, float><<<aggBlocks, TB, 0, stream>>>(Ah, B, att2, b2, rowptr, edst, perm, Cbf, N);

    // --- hierarchical global mean pool ---
    dim3 poolGrid(G, 16);
    k_pool_partial<<<poolGrid, TB, 0, stream>>>(Cbf, batch, pacc, N, 16);
    k_pool_final<<<G, 64, 0, stream>>>(pacc, batch, (float*)d_out, N);
}